// Round 2
// baseline (431.193 us; speedup 1.0000x reference)
//
#include <hip/hip_runtime.h>
#include <cstdint>

#define N_EDGES 12288
#define ROWLEN  2432      // 19*128 floats per edge
#define CAP     2048      // per-system bucket capacity (buckets avg 768)

typedef __bf16 bf16;
typedef __bf16 bf16x8 __attribute__((ext_vector_type(8)));
typedef float  f32x4  __attribute__((ext_vector_type(4)));

#define ELEMS0 (640*640)
#define ELEMS1 (1024*1024)
#define ELEMS2 (768*768)

// ws byte offsets
#define WS_IDX_OFF   1024
#define WS_BIAS_OFF  (WS_IDX_OFF + 16*CAP*4)        // 132096
#define WS_W_OFF     (WS_BIAS_OFF + 16*640*4)       // 173056 (16B aligned)

// After the SO(2) "hat" fold every branch is a square GEMM with K == N.
// NT = number of 128-col chunks; blocks cover 256-col pairs (2 chunks).
template<int B> struct Cfg;
template<> struct Cfg<0> { static constexpr int K=640,  KS=640, XOFF=0,    NT=5;
                           static constexpr size_t WOFF=0; };
template<> struct Cfg<1> { static constexpr int K=1024, KS=512, XOFF=640,  NT=8;
                           static constexpr size_t WOFF=(size_t)16*ELEMS0; };
template<> struct Cfg<2> { static constexpr int K=768,  KS=384, XOFF=1664, NT=6;
                           static constexpr size_t WOFF=(size_t)16*ELEMS0+(size_t)16*ELEMS1; };

__device__ __forceinline__ void async_copy16(const void* g, void* l) {
  // global -> LDS direct copy, 16B per lane; LDS dest = wave-uniform base + lane*16.
  auto gp = reinterpret_cast<const __attribute__((address_space(1))) unsigned int*>(
      reinterpret_cast<uintptr_t>(g));
  auto lp = reinterpret_cast<__attribute__((address_space(3))) unsigned int*>(
      (unsigned int)reinterpret_cast<uintptr_t>(l));
  __builtin_amdgcn_global_load_lds(gp, lp, 16, 0, 0);
}

// ---------------- bucketing ----------------
__global__ void bucket_kernel(const int* __restrict__ eb, int* __restrict__ counts,
                              int* __restrict__ idxb) {
  int t = blockIdx.x * 256 + threadIdx.x;
  if (t < N_EDGES) {
    int s = eb[t];
    int p = atomicAdd(counts + s, 1);
    if (p < CAP) idxb[s * CAP + p] = t;
  }
}

// ---------------- mixed bias ----------------
__global__ void bias_kernel(const float* __restrict__ ce, const float* __restrict__ b0,
                            float* __restrict__ bias) {
  int t = blockIdx.x * 256 + threadIdx.x;   // 0..10239
  int s = t / 640, c = t - s * 640;
  float a = 0.f;
#pragma unroll
  for (int e = 0; e < 8; ++e) a += ce[s * 8 + e] * b0[e * 640 + c];
  bias[t] = a;
}

// ---------------- weight mixing + hat fold + swizzle + bf16 cast ----------------
// dst layout per (branch, system): [kblk][chunk128][kgrp:4][n:128][k8:8] bf16.
template<int B>
__device__ __forceinline__ void mix_body(const float* __restrict__ Wsrc,
                                         const float* ce_s,
                                         unsigned short* __restrict__ Wz, int pos) {
  constexpr int N = Cfg<B>::K, KS = Cfg<B>::KS, NT = N / 128, HALF = N / 2;
  constexpr int SRC_STRIDE = KS * N;
  constexpr size_t DST_STRIDE = (size_t)Cfg<B>::K * N;
  int nn = pos & 127, kgrp = (pos >> 7) & 3, rest = pos >> 9;
  int nt = rest % NT, kblk = rest / NT;
  int i0 = kblk * 32 + kgrp * 8;
  int c  = nt * 128 + nn;
  int si = i0, sc = c; float sg = 1.f;
  if (B > 0 && i0 >= KS) {                      // lower half of hat: [-W2 | W1]
    si = i0 - KS;
    if (c < HALF) { sc = c + HALF; sg = -1.f; } else { sc = c - HALF; }
  }
  float w[8][8];
  const float* p0 = Wsrc + (size_t)si * N + sc;
#pragma unroll
  for (int e = 0; e < 8; ++e) {
    const float* p = p0 + (size_t)e * SRC_STRIDE;
#pragma unroll
    for (int j = 0; j < 8; ++j) w[e][j] = sg * p[(size_t)j * N];
  }
  unsigned short* db = Wz + Cfg<B>::WOFF + (size_t)pos * 8;
#pragma unroll
  for (int s = 0; s < 16; ++s) {
    float a[8] = {0, 0, 0, 0, 0, 0, 0, 0};
#pragma unroll
    for (int e = 0; e < 8; ++e) {
      float cc = ce_s[s * 8 + e];
#pragma unroll
      for (int j = 0; j < 8; ++j) a[j] += cc * w[e][j];
    }
    bf16x8 v;
#pragma unroll
    for (int j = 0; j < 8; ++j) v[j] = (bf16)a[j];
    *(bf16x8*)(db + s * DST_STRIDE) = v;
  }
}

__global__ __launch_bounds__(256) void mix_all(const float* __restrict__ W0,
                                               const float* __restrict__ W1,
                                               const float* __restrict__ W2,
                                               const float* __restrict__ ce,
                                               unsigned short* __restrict__ Wz) {
  __shared__ float ce_s[128];
  int tid = threadIdx.x;
  if (tid < 128) ce_s[tid] = ce[tid];
  __syncthreads();
  int bx = blockIdx.x;
  if (bx < 200)      mix_body<0>(W0, ce_s, Wz, bx * 256 + tid);
  else if (bx < 712) mix_body<1>(W1, ce_s, Wz, (bx - 200) * 256 + tid);
  else               mix_body<2>(W2, ce_s, Wz, (bx - 712) * 256 + tid);
}

// ---------------- grouped GEMM, 256x256 tile, 512 threads ----------------
template<int B>
__device__ __forceinline__ void gemm_body(const float* __restrict__ x,
                                          const unsigned short* __restrict__ Wz,
                                          const int* __restrict__ counts,
                                          const int* __restrict__ idxb,
                                          const float* __restrict__ bias,
                                          float* __restrict__ out,
                                          int s, int mt, int ntl2,
                                          bf16* lA, bf16* lB, int* eidx) {
  constexpr int K = Cfg<B>::K, NT = Cfg<B>::NT, KB = K / 32, XOFF = Cfg<B>::XOFF;
  int cnt = counts[s];
  int m0 = mt * 256;
  if (m0 >= cnt) return;
  int tid = threadIdx.x;
  if (tid < 256) eidx[tid] = (m0 + tid < cnt) ? idxb[s * CAP + m0 + tid] : -1;
  __syncthreads();
  int wv = tid >> 6, ln = tid & 63;
  int wm = wv >> 1, wn = wv & 1;          // wave computes rows wm*64.., chunk wn
  int kq = ln >> 4, lm = ln & 15;
  int ar = tid >> 1, ah = tid & 1;        // A staging: row 0..255, k-half
  int myedge = eidx[ar];
  bool av = myedge >= 0;
  const float* ap = x + (size_t)(av ? myedge : 0) * ROWLEN + XOFF + ah * 16;
  int c0 = 2 * ntl2;
  int myc = wv >> 2, q = wv & 3;          // B staging: wave stages quarter q of chunk myc
  bool bval = (c0 + myc) < NT;
  const bf16* wbase = (const bf16*)Wz + Cfg<B>::WOFF + (size_t)s * K * K;
  const bf16* gB0 = wbase + (size_t)(c0 + myc) * 4096 + (size_t)q * 1024;
  bf16* lBd = lB + myc * 4096 + q * 1024;

  f32x4 acc[4][8];
#pragma unroll
  for (int i = 0; i < 4; ++i)
#pragma unroll
    for (int j = 0; j < 8; ++j) {
      acc[i][j][0] = 0.f; acc[i][j][1] = 0.f; acc[i][j][2] = 0.f; acc[i][j][3] = 0.f;
    }

#pragma unroll 1
  for (int kb = 0; kb < KB; ++kb) {
    if (bval) {
      const bf16* g = gB0 + (size_t)kb * (NT * 4096);
      async_copy16(g + ln * 8, lBd);
      async_copy16(g + 512 + ln * 8, lBd + 512);
    }
    float4 f0 = {0,0,0,0}, f1 = {0,0,0,0}, f2 = {0,0,0,0}, f3 = {0,0,0,0};
    if (av) {
      const float4* p = (const float4*)(ap + kb * 32);
      f0 = p[0]; f1 = p[1]; f2 = p[2]; f3 = p[3];
    }
    bf16x8 v0, v1;
    v0[0]=(bf16)f0.x; v0[1]=(bf16)f0.y; v0[2]=(bf16)f0.z; v0[3]=(bf16)f0.w;
    v0[4]=(bf16)f1.x; v0[5]=(bf16)f1.y; v0[6]=(bf16)f1.z; v0[7]=(bf16)f1.w;
    v1[0]=(bf16)f2.x; v1[1]=(bf16)f2.y; v1[2]=(bf16)f2.z; v1[3]=(bf16)f2.w;
    v1[4]=(bf16)f3.x; v1[5]=(bf16)f3.y; v1[6]=(bf16)f3.z; v1[7]=(bf16)f3.w;
    *(bf16x8*)&lA[(ah * 2) * 2048 + ar * 8] = v0;
    *(bf16x8*)&lA[(ah * 2 + 1) * 2048 + ar * 8] = v1;
    __syncthreads();
    bf16x8 af[4], bq[8];
#pragma unroll
    for (int mi = 0; mi < 4; ++mi)
      af[mi] = *(const bf16x8*)&lA[kq * 2048 + (wm * 64 + mi * 16 + lm) * 8];
#pragma unroll
    for (int ni = 0; ni < 8; ++ni)
      bq[ni] = *(const bf16x8*)&lB[wn * 4096 + kq * 1024 + (ni * 16 + lm) * 8];
#pragma unroll
    for (int mi = 0; mi < 4; ++mi)
#pragma unroll
      for (int ni = 0; ni < 8; ++ni)
        acc[mi][ni] = __builtin_amdgcn_mfma_f32_16x16x32_bf16(af[mi], bq[ni], acc[mi][ni], 0, 0, 0);
    __syncthreads();
  }
  // epilogue: C/D layout col=lane&15, row=(lane>>4)*4+reg
  bool cval = (c0 + wn) < NT;
  if (!cval) return;
  float bv[8] = {0, 0, 0, 0, 0, 0, 0, 0};
  if (B == 0) {
#pragma unroll
    for (int ni = 0; ni < 8; ++ni)
      bv[ni] = bias[s * 640 + (c0 + wn) * 128 + ni * 16 + lm];
  }
#pragma unroll
  for (int mi = 0; mi < 4; ++mi) {
#pragma unroll
    for (int r = 0; r < 4; ++r) {
      int row = wm * 64 + mi * 16 + kq * 4 + r;
      int e = eidx[row];
      if (e < 0) continue;
      float* po = out + (size_t)e * ROWLEN + XOFF + (c0 + wn) * 128 + lm;
#pragma unroll
      for (int ni = 0; ni < 8; ++ni) po[ni * 16] = acc[mi][ni][r] + bv[ni];
    }
  }
}

__global__ __launch_bounds__(512) void gemm_all(const float* __restrict__ x,
                                                const unsigned short* __restrict__ Wz,
                                                const int* __restrict__ counts,
                                                const int* __restrict__ idxb,
                                                const float* __restrict__ bias,
                                                float* __restrict__ out) {
  __shared__ bf16 lA[8192];   // 16KB: [kgrp4][m256][k8]
  __shared__ bf16 lB[8192];   // 16KB: [chunk2][kgrp4][n128][k8]
  __shared__ int eidx[256];
  int id = blockIdx.x;
  int bx = id % 10;           // fastest-varying: blocks sharing A rows are adjacent
  int gid = id / 10;
  int y = gid & 7, s = gid >> 3;
  if (bx < 3)      gemm_body<0>(x, Wz, counts, idxb, bias, out, s, y, bx,     lA, lB, eidx);
  else if (bx < 7) gemm_body<1>(x, Wz, counts, idxb, bias, out, s, y, bx - 3, lA, lB, eidx);
  else             gemm_body<2>(x, Wz, counts, idxb, bias, out, s, y, bx - 7, lA, lB, eidx);
}

extern "C" void kernel_launch(void* const* d_in, const int* in_sizes, int n_in,
                              void* d_out, int out_size, void* d_ws, size_t ws_size,
                              hipStream_t stream) {
  const float* x  = (const float*)d_in[0];
  // d_in[1] = x_edge: unused by the reference
  const float* ce = (const float*)d_in[2];
  const int*   eb = (const int*)d_in[3];
  const float* W0 = (const float*)d_in[4];
  const float* b0 = (const float*)d_in[5];
  const float* W1 = (const float*)d_in[6];
  const float* W2 = (const float*)d_in[7];
  float* out = (float*)d_out;
  char* ws = (char*)d_ws;
  int*   counts = (int*)ws;
  int*   idxb   = (int*)(ws + WS_IDX_OFF);
  float* bias   = (float*)(ws + WS_BIAS_OFF);
  unsigned short* Wz = (unsigned short*)(ws + WS_W_OFF);

  hipMemsetAsync(counts, 0, 64, stream);
  bucket_kernel<<<48, 256, 0, stream>>>(eb, counts, idxb);
  bias_kernel<<<40, 256, 0, stream>>>(ce, b0, bias);
  mix_all<<<1000, 256, 0, stream>>>(W0, W1, W2, ce, Wz);
  gemm_all<<<1280, 512, 0, stream>>>(x, Wz, counts, idxb, bias, out);
}

// Round 3
// 396.470 us; speedup vs baseline: 1.0876x; 1.0876x over previous
//
#include <hip/hip_runtime.h>
#include <cstdint>

#define N_EDGES 12288
#define ROWLEN  2432      // 19*128 floats per edge
#define CAP     2048      // per-system bucket capacity (buckets avg 768)

typedef __bf16 bf16;
typedef __bf16 bf16x8 __attribute__((ext_vector_type(8)));
typedef float  f32x4  __attribute__((ext_vector_type(4)));

#define ELEMS0 (640*640)
#define ELEMS1 (1024*1024)
#define ELEMS2 (768*768)

// ws byte offsets
#define WS_IDX_OFF   1024
#define WS_BIAS_OFF  (WS_IDX_OFF + 16*CAP*4)                 // 132096
#define WS_W_OFF     (WS_BIAS_OFF + 16*640*4)                // 173056
#define WZ_ELEMS     ((size_t)16*(ELEMS0+ELEMS1+ELEMS2))     // 32.77M bf16
#define WS_XB_OFF    (WS_W_OFF + WZ_ELEMS*2)                 // 65,709,056
#define WS_NEED      (WS_XB_OFF + (size_t)N_EDGES*ROWLEN*2)  // ~125.5 MB

// After the SO(2) "hat" fold every branch is a square GEMM with K == N.
template<int B> struct Cfg;
template<> struct Cfg<0> { static constexpr int K=640,  KS=640, XOFF=0,    NT=5;
                           static constexpr size_t WOFF=0; };
template<> struct Cfg<1> { static constexpr int K=1024, KS=512, XOFF=640,  NT=8;
                           static constexpr size_t WOFF=(size_t)16*ELEMS0; };
template<> struct Cfg<2> { static constexpr int K=768,  KS=384, XOFF=1664, NT=6;
                           static constexpr size_t WOFF=(size_t)16*ELEMS0+(size_t)16*ELEMS1; };

__device__ __forceinline__ void async_copy16(const void* g, void* l) {
  // global -> LDS direct copy, 16B/lane; LDS dest = wave-uniform base + lane*16.
  // Source address may be fully per-lane scattered (VGPR address).
  auto gp = reinterpret_cast<const __attribute__((address_space(1))) unsigned int*>(
      reinterpret_cast<uintptr_t>(g));
  auto lp = reinterpret_cast<__attribute__((address_space(3))) unsigned int*>(
      (unsigned int)reinterpret_cast<uintptr_t>(l));
  __builtin_amdgcn_global_load_lds(gp, lp, 16, 0, 0);
}

// ---------------- bucketing ----------------
__global__ void bucket_kernel(const int* __restrict__ eb, int* __restrict__ counts,
                              int* __restrict__ idxb) {
  int t = blockIdx.x * 256 + threadIdx.x;
  if (t < N_EDGES) {
    int s = eb[t];
    int p = atomicAdd(counts + s, 1);
    if (p < CAP) idxb[s * CAP + p] = t;
  }
}

// ---------------- mixed bias ----------------
__global__ void bias_kernel(const float* __restrict__ ce, const float* __restrict__ b0,
                            float* __restrict__ bias) {
  int t = blockIdx.x * 256 + threadIdx.x;   // 0..10239
  int s = t / 640, c = t - s * 640;
  float a = 0.f;
#pragma unroll
  for (int e = 0; e < 8; ++e) a += ce[s * 8 + e] * b0[e * 640 + c];
  bias[t] = a;
}

// ---------------- x fp32 -> bf16 pre-cast ----------------
__global__ void cast_x(const float* __restrict__ x, bf16* __restrict__ xb) {
  size_t t = (size_t)blockIdx.x * 256 + threadIdx.x;   // one bf16x8 per thread
  const f32x4* xp = (const f32x4*)x;
  f32x4 a = xp[2 * t], b = xp[2 * t + 1];
  bf16x8 v;
  v[0]=(bf16)a[0]; v[1]=(bf16)a[1]; v[2]=(bf16)a[2]; v[3]=(bf16)a[3];
  v[4]=(bf16)b[0]; v[5]=(bf16)b[1]; v[6]=(bf16)b[2]; v[7]=(bf16)b[3];
  ((bf16x8*)xb)[t] = v;
}

// ---------------- weight mixing + hat fold + swizzle + bf16 cast ----------------
// dst layout per (branch, system): [kblk][chunk128][kgrp:4][n:128][k8:8] bf16.
template<int B>
__device__ __forceinline__ void mix_body(const float* __restrict__ Wsrc,
                                         const float* ce_s,
                                         unsigned short* __restrict__ Wz, int pos) {
  constexpr int N = Cfg<B>::K, KS = Cfg<B>::KS, NT = N / 128, HALF = N / 2;
  constexpr int SRC_STRIDE = KS * N;
  constexpr size_t DST_STRIDE = (size_t)Cfg<B>::K * N;
  int nn = pos & 127, kgrp = (pos >> 7) & 3, rest = pos >> 9;
  int nt = rest % NT, kblk = rest / NT;
  int i0 = kblk * 32 + kgrp * 8;
  int c  = nt * 128 + nn;
  int si = i0, sc = c; float sg = 1.f;
  if (B > 0 && i0 >= KS) {                      // lower half of hat: [-W2 | W1]
    si = i0 - KS;
    if (c < HALF) { sc = c + HALF; sg = -1.f; } else { sc = c - HALF; }
  }
  float w[8][8];
  const float* p0 = Wsrc + (size_t)si * N + sc;
#pragma unroll
  for (int e = 0; e < 8; ++e) {
    const float* p = p0 + (size_t)e * SRC_STRIDE;
#pragma unroll
    for (int j = 0; j < 8; ++j) w[e][j] = sg * p[(size_t)j * N];
  }
  unsigned short* db = Wz + Cfg<B>::WOFF + (size_t)pos * 8;
#pragma unroll
  for (int s = 0; s < 16; ++s) {
    float a[8] = {0, 0, 0, 0, 0, 0, 0, 0};
#pragma unroll
    for (int e = 0; e < 8; ++e) {
      float cc = ce_s[s * 8 + e];
#pragma unroll
      for (int j = 0; j < 8; ++j) a[j] += cc * w[e][j];
    }
    bf16x8 v;
#pragma unroll
    for (int j = 0; j < 8; ++j) v[j] = (bf16)a[j];
    *(bf16x8*)(db + s * DST_STRIDE) = v;
  }
}

__global__ __launch_bounds__(256) void mix_all(const float* __restrict__ W0,
                                               const float* __restrict__ W1,
                                               const float* __restrict__ W2,
                                               const float* __restrict__ ce,
                                               unsigned short* __restrict__ Wz) {
  __shared__ float ce_s[128];
  int tid = threadIdx.x;
  if (tid < 128) ce_s[tid] = ce[tid];
  __syncthreads();
  int bx = blockIdx.x;
  if (bx < 200)      mix_body<0>(W0, ce_s, Wz, bx * 256 + tid);
  else if (bx < 712) mix_body<1>(W1, ce_s, Wz, (bx - 200) * 256 + tid);
  else               mix_body<2>(W2, ce_s, Wz, (bx - 712) * 256 + tid);
}

// ---------------- grouped GEMM: 128x256 tile, 4 waves, dbuf async A+B ----------
template<int B, typename AT>
__device__ __forceinline__ void gemm_body(
    const AT* __restrict__ xa, const char* __restrict__ zeros,
    const unsigned short* __restrict__ Wz,
    const int* __restrict__ counts, const int* __restrict__ idxb,
    const float* __restrict__ bias, float* __restrict__ out,
    int s, int mt, int nt2, char* sm, int* eidx)
{
  constexpr int K = Cfg<B>::K, NT = Cfg<B>::NT, KB = K / 32, XOFF = Cfg<B>::XOFF;
  constexpr int ASZ = 128 * 32 * (int)sizeof(AT);   // A tile bytes per buf
  int cnt = counts[s];
  int m0 = mt * 128;
  if (m0 >= cnt) return;
  int tid = threadIdx.x;
  if (tid < 128) eidx[tid] = (m0 + tid < cnt) ? idxb[s * CAP + m0 + tid] : -1;
  __syncthreads();
  char* lA0 = sm;            char* lA1 = sm + ASZ;
  char* lB0 = sm + 2 * ASZ;  char* lB1 = sm + 2 * ASZ + 16384;
  int wv = tid >> 6, ln = tid & 63;
  int wm = wv >> 1, wn = wv & 1;
  int kq = ln >> 4, lm = ln & 15;
  int c0 = nt2 * 2;
  // A source: per-thread row pointer (zeros region for pad rows, kinc=0)
  int r_a = (sizeof(AT) == 4) ? (tid >> 1) : (tid & 127);
  const char* arow; int kinc;
  { int e = eidx[r_a];
    if (e >= 0) { arow = (const char*)(xa + (size_t)e * ROWLEN + XOFF); kinc = 32 * (int)sizeof(AT); }
    else        { arow = zeros; kinc = 0; } }
  const unsigned short* wb = Wz + Cfg<B>::WOFF + (size_t)s * K * K;

  auto stageA = [&](int kb, char* dst) {
    const char* p = arow + (size_t)kb * kinc;
    if (sizeof(AT) == 4) {
      int off = (tid & 1) * 16;                 // half of the 32B k8-f32 group
#pragma unroll
      for (int i = 0; i < 4; ++i)               // g = i
        async_copy16(p + off + i * 32, dst + (i * 256 + wv * 64) * 16);
    } else {
      int hi = (tid >> 7) & 1;
#pragma unroll
      for (int i = 0; i < 2; ++i)               // g = 2i + hi
        async_copy16(p + (2 * i + hi) * 16, dst + (i * 256 + wv * 64) * 16);
    }
  };
  auto stageB = [&](int kb, char* dst) {
    const unsigned short* base = wb + (size_t)kb * (NT * 4096);
#pragma unroll
    for (int i = 0; i < 4; ++i) {
      int c = i * 256 + tid;
      int ck = c0 + (c >> 9); if (ck > NT - 1) ck = NT - 1;   // clamp (dup read, result discarded)
      async_copy16(base + (size_t)ck * 4096 + (c & 511) * 8,
                   dst + (i * 256 + wv * 64) * 16);
    }
  };

  f32x4 acc[4][8];
#pragma unroll
  for (int i = 0; i < 4; ++i)
#pragma unroll
    for (int j = 0; j < 8; ++j) {
      acc[i][j][0] = 0.f; acc[i][j][1] = 0.f; acc[i][j][2] = 0.f; acc[i][j][3] = 0.f;
    }

  stageA(0, lA0); stageB(0, lB0);
#pragma unroll 1
  for (int kb = 0; kb < KB; ++kb) {
    __syncthreads();                              // drains stage(kb) issued one iter ago
    char* la = (kb & 1) ? lA1 : lA0;
    char* lb = (kb & 1) ? lB1 : lB0;
    if (kb + 1 < KB) {                            // prefetch next tile into other buf
      stageA(kb + 1, (kb & 1) ? lA0 : lA1);
      stageB(kb + 1, (kb & 1) ? lB0 : lB1);
    }
    bf16x8 af[4], bq[8];
    if (sizeof(AT) == 4) {
#pragma unroll
      for (int mi = 0; mi < 4; ++mi) {
        const f32x4* fp = (const f32x4*)(la + kq * 4096 + (wm * 64 + mi * 16 + lm) * 32);
        f32x4 lo = fp[0], hv = fp[1];
        bf16x8 v;
        v[0]=(bf16)lo[0]; v[1]=(bf16)lo[1]; v[2]=(bf16)lo[2]; v[3]=(bf16)lo[3];
        v[4]=(bf16)hv[0]; v[5]=(bf16)hv[1]; v[6]=(bf16)hv[2]; v[7]=(bf16)hv[3];
        af[mi] = v;
      }
    } else {
#pragma unroll
      for (int mi = 0; mi < 4; ++mi)
        af[mi] = *(const bf16x8*)(la + kq * 2048 + (wm * 64 + mi * 16 + lm) * 16);
    }
#pragma unroll
    for (int ni = 0; ni < 8; ++ni)
      bq[ni] = *(const bf16x8*)(lb + wn * 8192 + kq * 2048 + (ni * 16 + lm) * 16);
#pragma unroll
    for (int mi = 0; mi < 4; ++mi)
#pragma unroll
      for (int ni = 0; ni < 8; ++ni)
        acc[mi][ni] = __builtin_amdgcn_mfma_f32_16x16x32_bf16(af[mi], bq[ni], acc[mi][ni], 0, 0, 0);
  }
  // epilogue: C/D layout col=lane&15, row=(lane>>4)*4+reg
  int cc = c0 + wn;
  if (cc >= NT) return;
  float bv[8] = {0, 0, 0, 0, 0, 0, 0, 0};
  if (B == 0) {
#pragma unroll
    for (int ni = 0; ni < 8; ++ni)
      bv[ni] = bias[s * 640 + cc * 128 + ni * 16 + lm];
  }
#pragma unroll
  for (int mi = 0; mi < 4; ++mi) {
#pragma unroll
    for (int r = 0; r < 4; ++r) {
      int row = wm * 64 + mi * 16 + kq * 4 + r;
      int e = eidx[row];
      if (e < 0) continue;
      float* po = out + (size_t)e * ROWLEN + XOFF + cc * 128 + lm;
#pragma unroll
      for (int ni = 0; ni < 8; ++ni) po[ni * 16] = acc[mi][ni][r] + bv[ni];
    }
  }
}

template<typename AT>
__global__ __launch_bounds__(256, 2) void gemm_all(
    const AT* __restrict__ xa, const char* __restrict__ zeros,
    const unsigned short* __restrict__ Wz,
    const int* __restrict__ counts, const int* __restrict__ idxb,
    const float* __restrict__ bias, float* __restrict__ out) {
  extern __shared__ char sm[];
  __shared__ int eidx[128];
  int bx = blockIdx.x, mt = blockIdx.y, s = blockIdx.z;  // bx: 3+4+3 col-pairs
  if (bx < 3)      gemm_body<0, AT>(xa, zeros, Wz, counts, idxb, bias, out, s, mt, bx,     sm, eidx);
  else if (bx < 7) gemm_body<1, AT>(xa, zeros, Wz, counts, idxb, bias, out, s, mt, bx - 3, sm, eidx);
  else             gemm_body<2, AT>(xa, zeros, Wz, counts, idxb, bias, out, s, mt, bx - 7, sm, eidx);
}

extern "C" void kernel_launch(void* const* d_in, const int* in_sizes, int n_in,
                              void* d_out, int out_size, void* d_ws, size_t ws_size,
                              hipStream_t stream) {
  const float* x  = (const float*)d_in[0];
  // d_in[1] = x_edge: unused by the reference
  const float* ce = (const float*)d_in[2];
  const int*   eb = (const int*)d_in[3];
  const float* W0 = (const float*)d_in[4];
  const float* b0 = (const float*)d_in[5];
  const float* W1 = (const float*)d_in[6];
  const float* W2 = (const float*)d_in[7];
  float* out = (float*)d_out;
  char* ws = (char*)d_ws;
  int*   counts = (int*)ws;
  char*  zeros  = ws + 256;                      // zeroed by the memset below
  int*   idxb   = (int*)(ws + WS_IDX_OFF);
  float* bias   = (float*)(ws + WS_BIAS_OFF);
  unsigned short* Wz = (unsigned short*)(ws + WS_W_OFF);
  bf16*  xb     = (bf16*)(ws + WS_XB_OFF);

  hipMemsetAsync(ws, 0, 1024, stream);           // counts + zeros region
  bucket_kernel<<<48, 256, 0, stream>>>(eb, counts, idxb);
  bias_kernel<<<40, 256, 0, stream>>>(ce, b0, bias);
  mix_all<<<1000, 256, 0, stream>>>(W0, W1, W2, ce, Wz);
  if (ws_size >= WS_NEED) {
    cast_x<<<N_EDGES * ROWLEN / 8 / 256, 256, 0, stream>>>(x, xb);
    gemm_all<bf16><<<dim3(10, 16, 16), 256, 2 * 8192 + 32768, stream>>>(
        xb, zeros, Wz, counts, idxb, bias, out);
  } else {
    gemm_all<float><<<dim3(10, 16, 16), 256, 2 * 16384 + 32768, stream>>>(
        x, zeros, Wz, counts, idxb, bias, out);
  }
}